// Round 6
// baseline (2415.856 us; speedup 1.0000x reference)
//
#include <hip/hip_runtime.h>
#include <hip/hip_fp16.h>
#include <hip/hip_cooperative_groups.h>
#include <cstddef>
#include <cstdint>

namespace cg = cooperative_groups;

#define BATCH 32

// Workspace layout (floats):
//   Xh : [16384][32] half4 (node-major)   = 1,048,576
//   Th : layer0 5 slices [n][32] half4; layers1-3 [n][32][32] halves = 10,485,760
//   X1 : 4,194,304   X2 : 1,048,576   X3 : 262,144
//   X4 : 131,072 ([32][4096] batch-major) P : 1,048,576 ([32][256][128])

struct alignas(8) half4 { __half2 lo, hi; };

__device__ __forceinline__ void h4f(const half4 h, float f[4]) {
  float2 a = __half22float2(h.lo);
  float2 c = __half22float2(h.hi);
  f[0] = a.x; f[1] = a.y; f[2] = c.x; f[3] = c.y;
}
__device__ __forceinline__ void fma4(float4& a, float s, const float4& w) {
  a.x += s * w.x; a.y += s * w.y; a.z += s * w.z; a.w += s * w.w;
}
__device__ __forceinline__ float4 relu4(const float4& a) {
  return make_float4(fmaxf(a.x, 0.f), fmaxf(a.y, 0.f), fmaxf(a.z, 0.f), fmaxf(a.w, 0.f));
}

// ============================ stage bodies ============================

__device__ __forceinline__ void st_transpose(
    const float* __restrict__ x, half4* __restrict__ xh, int t)
{
  int n = t >> 5, b = t & 31;
  const float* src = x + ((size_t)b * 16384 + n) * 3;
  half4 h;
  h.lo = __floats2half2_rn(src[0], src[1]);
  h.hi = __floats2half2_rn(src[2], 0.f);
  xh[t] = h;
}

__device__ __forceinline__ void st_cheb(
    const half4* __restrict__ Tin, const half4* __restrict__ Tpp,
    const int* __restrict__ ec, half4* __restrict__ Tout,
    float coef, float beta, int idx)
{
  int n = idx >> 5, b = idx & 31;
  const int2* e2 = (const int2*)(ec + n * 6);
  int2 ea = e2[0], eb = e2[1], ez = e2[2];
  int na[6];
  na[0] = ea.x; na[1] = ea.y; na[2] = eb.x;
  na[3] = eb.y; na[4] = ez.x; na[5] = ez.y;
  float s0 = 0.f, s1 = 0.f, s2 = 0.f;
#pragma unroll
  for (int d = 0; d < 6; ++d) {
    half4 v = Tin[(na[d] << 5) | b];
    float2 a = __half22float2(v.lo);
    float2 c = __half22float2(v.hi);
    s0 += a.x; s1 += a.y; s2 += c.x;
  }
  half4 p = Tpp[idx];
  float2 pa = __half22float2(p.lo);
  float2 pc = __half22float2(p.hi);
  half4 o;
  o.lo = __floats2half2_rn(coef * s0 + beta * pa.x, coef * s1 + beta * pa.y);
  o.hi = __floats2half2_rn(coef * s2 + beta * pc.x, 0.f);
  Tout[idx] = o;
}

__device__ __forceinline__ void st_pool0(
    const half4* __restrict__ Xh, const half4* __restrict__ T,
    const float* __restrict__ Ws, const float* __restrict__ bias,
    const int* __restrict__ pc, const float* __restrict__ pv,
    float* __restrict__ out, int t)
{
  constexpr int F4 = 8;                        // FOUT=32
  constexpr size_t SL = (size_t)16384 * 32;
  const float4* Ws4 = (const float4*)Ws;
  int fo4 = t % F4;
  int b   = (t / F4) % BATCH;
  int m   = t / (F4 * BATCH);
  int c0 = pc[m * 3 + 0], c1 = pc[m * 3 + 1], c2 = pc[m * 3 + 2];
  float v0 = pv[m * 3 + 0], v1 = pv[m * 3 + 1], v2 = pv[m * 3 + 2];
  float4 bi = ((const float4*)bias)[fo4];
  float4 a0 = bi, a1 = bi, a2 = bi;
#pragma unroll
  for (int k = 0; k < 6; ++k) {
    const half4* base = (k == 0) ? Xh : (T + (size_t)(k - 1) * SL);
    float r0[4], r1[4], r2[4];
    h4f(base[(c0 << 5) | b], r0);
    h4f(base[(c1 << 5) | b], r1);
    h4f(base[(c2 << 5) | b], r2);
#pragma unroll
    for (int f = 0; f < 3; ++f) {
      float4 w = Ws4[(k * 3 + f) * F4 + fo4];
      fma4(a0, r0[f], w);
      fma4(a1, r1[f], w);
      fma4(a2, r2[f], w);
    }
  }
  a0 = relu4(a0); a1 = relu4(a1); a2 = relu4(a2);
  float4 acc;
  acc.x = v0*a0.x + v1*a1.x + v2*a2.x;
  acc.y = v0*a0.y + v1*a1.y + v2*a2.y;
  acc.z = v0*a0.z + v1*a1.z + v2*a2.z;
  acc.w = v0*a0.w + v1*a1.w + v2*a2.w;
  ((float4*)out)[((size_t)m * BATCH + b) * F4 + fo4] = acc;
}

// pool(relu(conv)) FIN=32; WH: weights in LDS as half (24 KB) vs float
template<int N, int M, int FOUT, bool OUT_BM, bool WH>
__device__ __forceinline__ void st_pool32(
    const float* __restrict__ X, const __half* __restrict__ Th,
    const void* __restrict__ Ws, const float* __restrict__ bias,
    const int* __restrict__ pc, const float* __restrict__ pv,
    float* __restrict__ out, int t)
{
  constexpr int F4 = FOUT / 4;
  constexpr size_t SLH = (size_t)N * 32 * 32;
  const float4* Wsf = (const float4*)Ws;
  const half4* Wsh = (const half4*)Ws;
  const float4* X4p = (const float4*)X;
  int fo4 = t % F4;
  int b   = (t / F4) % BATCH;
  int m   = t / (F4 * BATCH);
  int c0 = pc[m * 3 + 0], c1 = pc[m * 3 + 1], c2 = pc[m * 3 + 2];
  float v0 = pv[m * 3 + 0], v1 = pv[m * 3 + 1], v2 = pv[m * 3 + 2];
  float4 bi = ((const float4*)bias)[fo4];
  float4 a0 = bi, a1 = bi, a2 = bi;
#define WGET(off) (WH ? ({ float wf[4]; h4f(Wsh[off], wf); make_float4(wf[0],wf[1],wf[2],wf[3]); }) : Wsf[off])
  // k = 0 from fp32 X
  {
    const float4* r0 = X4p + ((size_t)c0 * BATCH + b) * 8;
    const float4* r1 = X4p + ((size_t)c1 * BATCH + b) * 8;
    const float4* r2 = X4p + ((size_t)c2 * BATCH + b) * 8;
#pragma unroll
    for (int fi = 0; fi < 8; ++fi) {
      float4 t0 = r0[fi], t1 = r1[fi], t2 = r2[fi];
#pragma unroll
      for (int ff = 0; ff < 4; ++ff) {
        float4 w = WGET((fi * 4 + ff) * F4 + fo4);
        fma4(a0, ((const float*)&t0)[ff], w);
        fma4(a1, ((const float*)&t1)[ff], w);
        fma4(a2, ((const float*)&t2)[ff], w);
      }
    }
  }
  // k = 1..5 from fp16 T
#pragma unroll 1
  for (int k = 1; k < 6; ++k) {
    const half4* base = (const half4*)(Th + (size_t)(k - 1) * SLH);
    const half4* r0 = base + ((size_t)c0 * 32 + b) * 8;
    const half4* r1 = base + ((size_t)c1 * 32 + b) * 8;
    const half4* r2 = base + ((size_t)c2 * 32 + b) * 8;
#pragma unroll
    for (int q = 0; q < 8; ++q) {
      float f0[4], f1[4], f2[4];
      h4f(r0[q], f0); h4f(r1[q], f1); h4f(r2[q], f2);
#pragma unroll
      for (int ff = 0; ff < 4; ++ff) {
        float4 w = WGET(((k * 32) + q * 4 + ff) * F4 + fo4);
        fma4(a0, f0[ff], w);
        fma4(a1, f1[ff], w);
        fma4(a2, f2[ff], w);
      }
    }
  }
#undef WGET
  a0 = relu4(a0); a1 = relu4(a1); a2 = relu4(a2);
  float4 acc;
  acc.x = v0*a0.x + v1*a1.x + v2*a2.x;
  acc.y = v0*a0.y + v1*a1.y + v2*a2.y;
  acc.z = v0*a0.z + v1*a1.z + v2*a2.z;
  acc.w = v0*a0.w + v1*a1.w + v2*a2.w;
  size_t oi = OUT_BM ? (((size_t)b * M + m) * F4 + fo4) : (((size_t)m * BATCH + b) * F4 + fo4);
  ((float4*)out)[oi] = acc;
}

// LDS-resident Cheb recurrence, half4 cells (R5-verified logic)
template<int N, int THREADS>
__device__ void st_recur(
    const float* __restrict__ X, const int* __restrict__ ec,
    __half* __restrict__ Th, half4* cur, int bid, int tid)
{
  constexpr int NPT = N / THREADS;
  const float cI = -1.0f / 6.0f;
  const float cS = -1.0f / 3.0f;
  const int b = bid & 31;
  const int fbase = (bid >> 5) * 4;
  constexpr size_t SLH = (size_t)N * 32 * 32;
  half4 prevv[NPT], newh[NPT];
#pragma unroll
  for (int i = 0; i < NPT; ++i) {
    int n = tid + i * THREADS;
    float4 xv = *(const float4*)(X + ((size_t)n * 32 + b) * 32 + fbase);
    half4 h;
    h.lo = __floats2half2_rn(xv.x, xv.y);
    h.hi = __floats2half2_rn(xv.z, xv.w);
    cur[n] = h;
  }
  __syncthreads();
#pragma unroll 1
  for (int k = 1; k <= 5; ++k) {
    __half* Tk = Th + (size_t)(k - 1) * SLH;
#pragma unroll
    for (int i = 0; i < NPT; ++i) {
      int n = tid + i * THREADS;
      const int2* e2 = (const int2*)(ec + n * 6);
      int2 ea = e2[0], eb = e2[1], ez = e2[2];
      int na[6];
      na[0] = ea.x; na[1] = ea.y; na[2] = eb.x;
      na[3] = eb.y; na[4] = ez.x; na[5] = ez.y;
      float s0 = 0.f, s1 = 0.f, s2 = 0.f, s3 = 0.f;
#pragma unroll
      for (int d = 0; d < 6; ++d) {
        half4 t = cur[na[d]];
        float2 a = __half22float2(t.lo);
        float2 c = __half22float2(t.hi);
        s0 += a.x; s1 += a.y; s2 += c.x; s3 += c.y;
      }
      float v0, v1, v2, v3;
      if (k == 1) {
        v0 = cI * s0; v1 = cI * s1; v2 = cI * s2; v3 = cI * s3;
      } else {
        float2 pa = __half22float2(prevv[i].lo);
        float2 pc = __half22float2(prevv[i].hi);
        v0 = cS * s0 - pa.x; v1 = cS * s1 - pa.y;
        v2 = cS * s2 - pc.x; v3 = cS * s3 - pc.y;
      }
      half4 h;
      h.lo = __floats2half2_rn(v0, v1);
      h.hi = __floats2half2_rn(v2, v3);
      newh[i] = h;
      *(half4*)(Tk + ((size_t)n * 32 + b) * 32 + fbase) = h;
    }
    __syncthreads();
#pragma unroll
    for (int i = 0; i < NPT; ++i) {
      int n = tid + i * THREADS;
      prevv[i] = cur[n];
      cur[n] = newh[i];
    }
    __syncthreads();
  }
}

// weight-stationary encoder partial: block j owns encW rows [32j,32j+32)
__device__ void st_enc(
    const float* __restrict__ Xf, const float* __restrict__ encW,
    float* __restrict__ partial, int j, int tid)
{
  int fo = tid & 127;
  int rh = tid >> 7;                 // 0/1: rows 16 each
  int i0 = j * 32 + rh * 16;
  float w[16];
#pragma unroll
  for (int i = 0; i < 16; ++i) w[i] = encW[(size_t)(i0 + i) * 128 + fo];
#pragma unroll 1
  for (int b = 0; b < 32; ++b) {
    const float* xr = Xf + b * 4096 + i0;
    float s = 0.f;
#pragma unroll
    for (int i = 0; i < 16; ++i) s += xr[i] * w[i];
    partial[((size_t)b * 256 + (j * 2 + rh)) * 128 + fo] = s;
  }
}

__device__ void st_cls(
    const float* __restrict__ partial, const float* __restrict__ encB,
    const float* __restrict__ clsW, const float* __restrict__ clsB,
    float* __restrict__ out, int b, int tid, float* Hs)
{
  if (tid < 128) {
    float acc = encB[tid];
#pragma unroll 8
    for (int jj = 0; jj < 256; ++jj)
      acc += partial[((size_t)b * 256 + jj) * 128 + tid];
    Hs[tid] = fmaxf(acc, 0.f);
  }
  __syncthreads();
  if (tid < 10) {
    float s = clsB[tid];
#pragma unroll 4
    for (int f = 0; f < 128; ++f) s += Hs[f] * clsW[f * 10 + tid];
    out[b * 10 + tid] = s;
  }
}

// ============================ K1: layer-0 chain (coop, full TLP) ============================
// 2048 blocks x 256 thr = 8 blocks/CU = 32 waves/CU — SAME TLP as the
// separate dispatches; only the 6 boundaries are replaced by grid.sync.
struct K1P {
  const float* x; const int* ec0;
  const float *W0, *b0; const int* pc0; const float* pv0;
  half4* Xh; half4* T4; float* X1;
};

__global__ void __launch_bounds__(256, 8) k1_chain(K1P p)
{
  cg::grid_group g = cg::this_grid();
  __shared__ float Ws[576];
  const int idx = blockIdx.x * 256 + threadIdx.x;   // [0, 524288)
  for (int i = threadIdx.x; i < 576; i += 256) Ws[i] = p.W0[i];
  st_transpose(p.x, p.Xh, idx);
  g.sync();
  const size_t S = (size_t)16384 * 32;
  const float cI = -1.0f / 6.0f, cS = -1.0f / 3.0f;
  st_cheb(p.Xh,       p.Xh,       p.ec0, p.T4,        cI,  0.f, idx); g.sync();
  st_cheb(p.T4,       p.Xh,       p.ec0, p.T4 + S,    cS, -1.f, idx); g.sync();
  st_cheb(p.T4 + S,   p.T4,       p.ec0, p.T4 + 2*S,  cS, -1.f, idx); g.sync();
  st_cheb(p.T4 + 2*S, p.T4 + S,   p.ec0, p.T4 + 3*S,  cS, -1.f, idx); g.sync();
  st_cheb(p.T4 + 3*S, p.T4 + 2*S, p.ec0, p.T4 + 4*S,  cS, -1.f, idx); g.sync();
  st_pool0(p.Xh, p.T4, Ws, p.b0, p.pc0, p.pv0, p.X1, idx);
  st_pool0(p.Xh, p.T4, Ws, p.b0, p.pc0, p.pv0, p.X1, idx + 524288);
}

// ============================ K2: recur layer 1 (unchanged, verified) ============================
template<int N, int THREADS, int MINW>
__global__ void __launch_bounds__(THREADS, MINW) cheb_recur_g(
    const float* __restrict__ X, const int* __restrict__ ec,
    __half* __restrict__ Th)
{
  __shared__ half4 cur[N];
  st_recur<N, THREADS>(X, ec, Th, cur, blockIdx.x, threadIdx.x);
}

// ============================ K3: tail (coop) ============================
// 1024 blocks x 256 thr, 24 KB LDS union (>=4 blocks/CU guaranteed by
// launch_bounds(256,6): LDS cap 6/CU, VGPR<=85).
struct K3P {
  const float *X1; const __half* Th;
  const float *W1, *b1; const int* pc1; const float* pv1; float* X2;
  const int* ec2; const float *W2, *b2; const int* pc2; const float* pv2; float* X3;
  const int* ec3; const float *W3, *b3; const int* pc3; const float* pv3; float* X4;
  const float *encW, *encB, *clsW, *clsB; float* P; float* out;
};

__global__ void __launch_bounds__(256, 6) k3_tail(K3P p)
{
  cg::grid_group g = cg::this_grid();
  __shared__ __align__(16) char sm[24576];
  float* Wsf = (float*)sm;
  __half* Wsh = (__half*)sm;
  const int bid = blockIdx.x, tid = threadIdx.x;
  __half* Thm = (__half*)p.Th;

  // pool1: 1024 blocks
  for (int i = tid; i < 6144; i += 256) Wsf[i] = p.W1[i];
  __syncthreads();
  st_pool32<4096, 1024, 32, false, false>(p.X1, p.Th, sm, p.b1, p.pc1, p.pv1,
                                          p.X2, bid * 256 + tid);
  g.sync();
  // recur2: 256 blocks
  if (bid < 256) st_recur<1024, 256>(p.X2, p.ec2, Thm, (half4*)sm, bid, tid);
  g.sync();
  // pool2: 256 blocks
  for (int i = tid; i < 6144; i += 256) Wsf[i] = p.W2[i];
  __syncthreads();
  if (bid < 256)
    st_pool32<1024, 256, 32, false, false>(p.X2, p.Th, sm, p.b2, p.pc2, p.pv2,
                                           p.X3, bid * 256 + tid);
  g.sync();
  // recur3: 256 blocks
  if (bid < 256) st_recur<256, 256>(p.X3, p.ec3, Thm, (half4*)sm, bid, tid);
  g.sync();
  // pool3: 128 blocks, FOUT=64, weights fp16 in LDS (24 KB)
  for (int i = tid; i < 12288; i += 256) Wsh[i] = __float2half(p.W3[i]);
  __syncthreads();
  if (bid < 128)
    st_pool32<256, 64, 64, true, true>(p.X3, p.Th, sm, p.b3, p.pc3, p.pv3,
                                       p.X4, bid * 256 + tid);
  g.sync();
  // encoder partials: 128 blocks
  if (bid < 128) st_enc(p.X4, p.encW, p.P, bid, tid);
  g.sync();
  // reduce + relu + classifier: 32 blocks
  if (bid < 32) st_cls(p.P, p.encB, p.clsW, p.clsB, p.out, bid, tid, (float*)sm);
}

// ============================ fallback kernels (R5-verified shapes) ============================

__global__ void __launch_bounds__(256) fb_transpose(
    const float* __restrict__ x, half4* __restrict__ xh)
{ st_transpose(x, xh, blockIdx.x * 256 + threadIdx.x); }

__global__ void __launch_bounds__(256) fb_cheb(
    const half4* __restrict__ Tin, const half4* __restrict__ Tpp,
    const int* __restrict__ ec, half4* __restrict__ Tout, float coef, float beta)
{ st_cheb(Tin, Tpp, ec, Tout, coef, beta, blockIdx.x * 256 + threadIdx.x); }

__global__ void __launch_bounds__(256) fb_pool0(
    const half4* __restrict__ Xh, const half4* __restrict__ T,
    const float* __restrict__ W, const float* __restrict__ bias,
    const int* __restrict__ pc, const float* __restrict__ pv,
    float* __restrict__ out)
{
  __shared__ float Ws[576];
  for (int i = threadIdx.x; i < 576; i += 256) Ws[i] = W[i];
  __syncthreads();
  st_pool0(Xh, T, Ws, bias, pc, pv, out, blockIdx.x * 256 + threadIdx.x);
}

template<int N, int M, int FOUT, bool OUT_BM>
__global__ void __launch_bounds__(256) fb_pool32(
    const float* __restrict__ X, const __half* __restrict__ Th,
    const float* __restrict__ W, const float* __restrict__ bias,
    const int* __restrict__ pc, const float* __restrict__ pv,
    float* __restrict__ out)
{
  __shared__ float Ws[6 * 32 * FOUT];
  for (int i = threadIdx.x; i < 6 * 32 * FOUT; i += 256) Ws[i] = W[i];
  __syncthreads();
  st_pool32<N, M, FOUT, OUT_BM, false>(X, Th, Ws, bias, pc, pv, out,
                                       blockIdx.x * 256 + threadIdx.x);
}

__global__ void __launch_bounds__(256) fb_enc(
    const float* __restrict__ Xf, const float* __restrict__ encW,
    float* __restrict__ partial)
{ st_enc(Xf, encW, partial, blockIdx.x, threadIdx.x); }

__global__ void __launch_bounds__(256) fb_cls(
    const float* __restrict__ partial, const float* __restrict__ encB,
    const float* __restrict__ clsW, const float* __restrict__ clsB,
    float* __restrict__ out)
{
  __shared__ float Hs[128];
  st_cls(partial, encB, clsW, clsB, out, blockIdx.x, threadIdx.x, Hs);
}

// ============================ launcher ============================

extern "C" void kernel_launch(void* const* d_in, const int* in_sizes, int n_in,
                              void* d_out, int out_size, void* d_ws, size_t ws_size,
                              hipStream_t stream)
{
  const float* x   = (const float*)d_in[0];
  const int* ec0 = (const int*)d_in[2];
  const int* ec1 = (const int*)d_in[4];
  const int* ec2 = (const int*)d_in[6];
  const int* ec3 = (const int*)d_in[8];
  const int* pc0 = (const int*)d_in[10]; const float* pv0 = (const float*)d_in[11];
  const int* pc1 = (const int*)d_in[13]; const float* pv1 = (const float*)d_in[14];
  const int* pc2 = (const int*)d_in[16]; const float* pv2 = (const float*)d_in[17];
  const int* pc3 = (const int*)d_in[19]; const float* pv3 = (const float*)d_in[20];
  const float* W0 = (const float*)d_in[21]; const float* b0 = (const float*)d_in[22];
  const float* W1 = (const float*)d_in[23]; const float* b1 = (const float*)d_in[24];
  const float* W2 = (const float*)d_in[25]; const float* b2 = (const float*)d_in[26];
  const float* W3 = (const float*)d_in[27]; const float* b3 = (const float*)d_in[28];
  const float* encW = (const float*)d_in[29]; const float* encB = (const float*)d_in[30];
  const float* clsW = (const float*)d_in[31]; const float* clsB = (const float*)d_in[32];
  float* out = (float*)d_out;

  float* ws = (float*)d_ws;
  half4*  Xh = (half4*)ws;               // 1,048,576 floats
  __half* Th = (__half*)(ws + 1048576);  // 10,485,760 floats
  float* X1 = ws + 1048576 + 10485760;   // 4,194,304
  float* X2 = X1 + 4194304;              // 1,048,576
  float* X3 = X2 + 1048576;              // 262,144
  float* X4 = X3 + 262144;               // 131,072
  float* P  = X4 + 131072;               // 1,048,576

  const float cI = -1.0f / 6.0f;
  const float cS = -1.0f / 3.0f;
  dim3 blk(256);
  constexpr size_t S = (size_t)16384 * 32;
  half4* T4 = (half4*)Th;

  // -------- K1: transpose + cheb x5 + pool0 --------
  K1P p1{ x, ec0, W0, b0, pc0, pv0, Xh, T4, X1 };
  void* a1[] = { (void*)&p1 };
  hipError_t e1 = hipLaunchCooperativeKernel((const void*)k1_chain,
                                             dim3(2048), blk, a1, 0, stream);
  if (e1 != hipSuccess) {
    (void)hipGetLastError();
    fb_transpose<<<dim3(2048), blk, 0, stream>>>(x, Xh);
    fb_cheb<<<dim3(2048), blk, 0, stream>>>(Xh,       Xh,       ec0, T4,        cI,  0.f);
    fb_cheb<<<dim3(2048), blk, 0, stream>>>(T4,       Xh,       ec0, T4 + S,    cS, -1.f);
    fb_cheb<<<dim3(2048), blk, 0, stream>>>(T4 + S,   T4,       ec0, T4 + 2*S,  cS, -1.f);
    fb_cheb<<<dim3(2048), blk, 0, stream>>>(T4 + 2*S, T4 + S,   ec0, T4 + 3*S,  cS, -1.f);
    fb_cheb<<<dim3(2048), blk, 0, stream>>>(T4 + 3*S, T4 + 2*S, ec0, T4 + 4*S,  cS, -1.f);
    fb_pool0<<<dim3(4096), blk, 0, stream>>>(Xh, T4, W0, b0, pc0, pv0, X1);
  }

  // -------- K2: recur layer 1 --------
  cheb_recur_g<4096, 1024, 4><<<dim3(256), dim3(1024), 0, stream>>>(X1, ec1, Th);

  // -------- K3: tail --------
  K3P p3{ X1, Th, W1, b1, pc1, pv1, X2,
          ec2, W2, b2, pc2, pv2, X3,
          ec3, W3, b3, pc3, pv3, X4,
          encW, encB, clsW, clsB, P, out };
  void* a3[] = { (void*)&p3 };
  hipError_t e3 = hipLaunchCooperativeKernel((const void*)k3_tail,
                                             dim3(1024), blk, a3, 0, stream);
  if (e3 != hipSuccess) {
    (void)hipGetLastError();
    fb_pool32<4096, 1024, 32, false><<<dim3(1024), blk, 0, stream>>>(
        X1, Th, W1, b1, pc1, pv1, X2);
    cheb_recur_g<1024, 256, 4><<<dim3(256), blk, 0, stream>>>(X2, ec2, Th);
    fb_pool32<1024, 256, 32, false><<<dim3(256), blk, 0, stream>>>(
        X2, Th, W2, b2, pc2, pv2, X3);
    cheb_recur_g<256, 256, 4><<<dim3(256), blk, 0, stream>>>(X3, ec3, Th);
    fb_pool32<256, 64, 64, true><<<dim3(128), blk, 0, stream>>>(
        X3, Th, W3, b3, pc3, pv3, X4);
    fb_enc<<<dim3(128), blk, 0, stream>>>(X4, encW, P);
    fb_cls<<<dim3(32), blk, 0, stream>>>(P, encB, clsW, clsB, out);
  }
}

// Round 7
// 642.995 us; speedup vs baseline: 3.7572x; 3.7572x over previous
//
#include <hip/hip_runtime.h>
#include <hip/hip_fp16.h>
#include <cstddef>
#include <cstdint>

#define BATCH 32

// Workspace layout (floats):
//   Xh : [16384][32] half4 (node-major)   = 1,048,576
//   Th : layer0 5 slices [n][32] half4; layers1-3 [n][32][32] halves = 10,485,760
//   X1 : 4,194,304   X2 : 1,048,576   X3 : 262,144
//   X4 : 131,072 ([32][4096] batch-major)
//
// Tail kernel: phases pool1..cls fused per-batch (32 blocks). All global
// intermediates (X2, X3, X4, recur2/3 T-slices) are written/read at
// b-disjoint 64B rows -> no cross-block races; intra-block RAW uses
// __threadfence()+__syncthreads() (same-CU L1/L2 visibility).

struct alignas(8) half4 { __half2 lo, hi; };

__device__ __forceinline__ void h4f(const half4 h, float f[4]) {
  float2 a = __half22float2(h.lo);
  float2 c = __half22float2(h.hi);
  f[0] = a.x; f[1] = a.y; f[2] = c.x; f[3] = c.y;
}
__device__ __forceinline__ void fma4(float4& a, float s, const float4& w) {
  a.x += s * w.x; a.y += s * w.y; a.z += s * w.z; a.w += s * w.w;
}
__device__ __forceinline__ float4 relu4(const float4& a) {
  return make_float4(fmaxf(a.x, 0.f), fmaxf(a.y, 0.f), fmaxf(a.z, 0.f), fmaxf(a.w, 0.f));
}

// ---------------- transpose x[b][n][3] -> Xh[n][32][4] fp16 (R1-verified) ----------------
__global__ void __launch_bounds__(256) transpose_h(
    const float* __restrict__ x, half4* __restrict__ xh)
{
  int t = blockIdx.x * 256 + threadIdx.x;   // n*32 + b
  int n = t >> 5;
  int b = t & 31;
  const float* src = x + ((size_t)b * 16384 + n) * 3;
  half4 h;
  h.lo = __floats2half2_rn(src[0], src[1]);
  h.hi = __floats2half2_rn(src[2], 0.f);
  xh[t] = h;
}

// ---------------- fp16 Cheb step, layer 0 (R1-verified) ----------------
__global__ void __launch_bounds__(256) cheb_step_h(
    const half4* __restrict__ Tin, const half4* __restrict__ Tpp,
    const int* __restrict__ ec, half4* __restrict__ Tout,
    float coef, float beta)
{
  int idx = blockIdx.x * 256 + threadIdx.x;   // n*32 + b, exact grid
  int n = idx >> 5;
  int b = idx & 31;
  const int2* e2 = (const int2*)(ec + n * 6);
  int2 ea = e2[0], eb = e2[1], ez = e2[2];
  int na[6];
  na[0] = ea.x; na[1] = ea.y; na[2] = eb.x;
  na[3] = eb.y; na[4] = ez.x; na[5] = ez.y;
  float s0 = 0.f, s1 = 0.f, s2 = 0.f;
#pragma unroll
  for (int d = 0; d < 6; ++d) {
    half4 v = Tin[(na[d] << 5) | b];
    float2 a = __half22float2(v.lo);
    float2 c = __half22float2(v.hi);
    s0 += a.x; s1 += a.y; s2 += c.x;
  }
  half4 p = Tpp[idx];
  float2 pa = __half22float2(p.lo);
  float2 pc = __half22float2(p.hi);
  half4 o;
  o.lo = __floats2half2_rn(coef * s0 + beta * pa.x, coef * s1 + beta * pa.y);
  o.hi = __floats2half2_rn(coef * s2 + beta * pc.x, 0.f);
  Tout[idx] = o;
}

// ---------------- fused pool(relu(conv)), FIN=3 (R1-verified) ----------------
__global__ void __launch_bounds__(256) pool_conv_f3_h(
    const half4* __restrict__ Xh, const half4* __restrict__ T,
    const float* __restrict__ W, const float* __restrict__ bias,
    const int* __restrict__ pc, const float* __restrict__ pv,
    float* __restrict__ out)
{
  constexpr int F4 = 8;                        // FOUT=32
  constexpr size_t SL = (size_t)16384 * 32;
  __shared__ float Ws[576];
  for (int i = threadIdx.x; i < 576; i += 256) Ws[i] = W[i];
  __syncthreads();
  const float4* Ws4 = (const float4*)Ws;
  int t = blockIdx.x * 256 + threadIdx.x;      // exact grid: 4096*32*8
  int fo4 = t % F4;
  int b   = (t / F4) % BATCH;
  int m   = t / (F4 * BATCH);
  int c0 = pc[m * 3 + 0], c1 = pc[m * 3 + 1], c2 = pc[m * 3 + 2];
  float v0 = pv[m * 3 + 0], v1 = pv[m * 3 + 1], v2 = pv[m * 3 + 2];
  float4 bi = ((const float4*)bias)[fo4];
  float4 a0 = bi, a1 = bi, a2 = bi;
#pragma unroll
  for (int k = 0; k < 6; ++k) {
    const half4* base = (k == 0) ? Xh : (T + (size_t)(k - 1) * SL);
    float r0[4], r1[4], r2[4];
    h4f(base[(c0 << 5) | b], r0);
    h4f(base[(c1 << 5) | b], r1);
    h4f(base[(c2 << 5) | b], r2);
#pragma unroll
    for (int f = 0; f < 3; ++f) {
      float4 w = Ws4[(k * 3 + f) * F4 + fo4];
      fma4(a0, r0[f], w);
      fma4(a1, r1[f], w);
      fma4(a2, r2[f], w);
    }
  }
  a0 = relu4(a0); a1 = relu4(a1); a2 = relu4(a2);
  float4 acc;
  acc.x = v0*a0.x + v1*a1.x + v2*a2.x;
  acc.y = v0*a0.y + v1*a1.y + v2*a2.y;
  acc.z = v0*a0.z + v1*a1.z + v2*a2.z;
  acc.w = v0*a0.w + v1*a1.w + v2*a2.w;
  ((float4*)out)[((size_t)m * BATCH + b) * F4 + fo4] = acc;
}

// ---------------- pool(relu(conv)) FIN=32 cell body (R5/R6-verified) ----------------
template<int N, int M, int FOUT, bool OUT_BM, bool WH>
__device__ __forceinline__ void st_pool32(
    const float* __restrict__ X, const __half* __restrict__ Th,
    const void* __restrict__ Ws, const float* __restrict__ bias,
    const int* __restrict__ pc, const float* __restrict__ pv,
    float* __restrict__ out, int t)
{
  constexpr int F4 = FOUT / 4;
  constexpr size_t SLH = (size_t)N * 32 * 32;
  const float4* Wsf = (const float4*)Ws;
  const half4* Wsh = (const half4*)Ws;
  const float4* X4p = (const float4*)X;
  int fo4 = t % F4;
  int b   = (t / F4) % BATCH;
  int m   = t / (F4 * BATCH);
  int c0 = pc[m * 3 + 0], c1 = pc[m * 3 + 1], c2 = pc[m * 3 + 2];
  float v0 = pv[m * 3 + 0], v1 = pv[m * 3 + 1], v2 = pv[m * 3 + 2];
  float4 bi = ((const float4*)bias)[fo4];
  float4 a0 = bi, a1 = bi, a2 = bi;
#define WGET(off) (WH ? ({ float wf[4]; h4f(Wsh[off], wf); make_float4(wf[0],wf[1],wf[2],wf[3]); }) : Wsf[off])
  {
    const float4* r0 = X4p + ((size_t)c0 * BATCH + b) * 8;
    const float4* r1 = X4p + ((size_t)c1 * BATCH + b) * 8;
    const float4* r2 = X4p + ((size_t)c2 * BATCH + b) * 8;
#pragma unroll
    for (int fi = 0; fi < 8; ++fi) {
      float4 t0 = r0[fi], t1 = r1[fi], t2 = r2[fi];
#pragma unroll
      for (int ff = 0; ff < 4; ++ff) {
        float4 w = WGET((fi * 4 + ff) * F4 + fo4);
        fma4(a0, ((const float*)&t0)[ff], w);
        fma4(a1, ((const float*)&t1)[ff], w);
        fma4(a2, ((const float*)&t2)[ff], w);
      }
    }
  }
#pragma unroll 1
  for (int k = 1; k < 6; ++k) {
    const half4* base = (const half4*)(Th + (size_t)(k - 1) * SLH);
    const half4* r0 = base + ((size_t)c0 * 32 + b) * 8;
    const half4* r1 = base + ((size_t)c1 * 32 + b) * 8;
    const half4* r2 = base + ((size_t)c2 * 32 + b) * 8;
#pragma unroll
    for (int q = 0; q < 8; ++q) {
      float f0[4], f1[4], f2[4];
      h4f(r0[q], f0); h4f(r1[q], f1); h4f(r2[q], f2);
#pragma unroll
      for (int ff = 0; ff < 4; ++ff) {
        float4 w = WGET(((k * 32) + q * 4 + ff) * F4 + fo4);
        fma4(a0, f0[ff], w);
        fma4(a1, f1[ff], w);
        fma4(a2, f2[ff], w);
      }
    }
  }
#undef WGET
  a0 = relu4(a0); a1 = relu4(a1); a2 = relu4(a2);
  float4 acc;
  acc.x = v0*a0.x + v1*a1.x + v2*a2.x;
  acc.y = v0*a0.y + v1*a1.y + v2*a2.y;
  acc.z = v0*a0.z + v1*a1.z + v2*a2.z;
  acc.w = v0*a0.w + v1*a1.w + v2*a2.w;
  size_t oi = OUT_BM ? (((size_t)b * M + m) * F4 + fo4) : (((size_t)m * BATCH + b) * F4 + fo4);
  ((float4*)out)[oi] = acc;
}

// ---------------- LDS Cheb recurrence, layer 1 (R5-verified, unchanged) ----------------
template<int N, int F, int THREADS, int MINW>
__global__ void __launch_bounds__(THREADS, MINW) cheb_recur_hh(
    const float* __restrict__ X, const int* __restrict__ ec,
    __half* __restrict__ Th)
{
  constexpr int NPT = N / THREADS;
  __shared__ half4 cur[N];
  const float cI = -1.0f / 6.0f;
  const float cS = -1.0f / 3.0f;
  const int b = blockIdx.x & 31;
  const int fbase = (blockIdx.x >> 5) * 4;
  constexpr size_t SLH = (size_t)N * 32 * F;
  half4 prevv[NPT], newh[NPT];
#pragma unroll
  for (int i = 0; i < NPT; ++i) {
    int n = threadIdx.x + i * THREADS;
    float4 xv = *(const float4*)(X + ((size_t)n * 32 + b) * F + fbase);
    half4 h;
    h.lo = __floats2half2_rn(xv.x, xv.y);
    h.hi = __floats2half2_rn(xv.z, xv.w);
    cur[n] = h;
  }
  __syncthreads();
#pragma unroll 1
  for (int k = 1; k <= 5; ++k) {
    __half* Tk = Th + (size_t)(k - 1) * SLH;
#pragma unroll
    for (int i = 0; i < NPT; ++i) {
      int n = threadIdx.x + i * THREADS;
      const int2* e2 = (const int2*)(ec + n * 6);
      int2 ea = e2[0], eb = e2[1], ez = e2[2];
      int na[6];
      na[0] = ea.x; na[1] = ea.y; na[2] = eb.x;
      na[3] = eb.y; na[4] = ez.x; na[5] = ez.y;
      float s0 = 0.f, s1 = 0.f, s2 = 0.f, s3 = 0.f;
#pragma unroll
      for (int d = 0; d < 6; ++d) {
        half4 t = cur[na[d]];
        float2 a = __half22float2(t.lo);
        float2 c = __half22float2(t.hi);
        s0 += a.x; s1 += a.y; s2 += c.x; s3 += c.y;
      }
      float v0, v1, v2, v3;
      if (k == 1) {
        v0 = cI * s0; v1 = cI * s1; v2 = cI * s2; v3 = cI * s3;
      } else {
        float2 pa = __half22float2(prevv[i].lo);
        float2 pc = __half22float2(prevv[i].hi);
        v0 = cS * s0 - pa.x; v1 = cS * s1 - pa.y;
        v2 = cS * s2 - pc.x; v3 = cS * s3 - pc.y;
      }
      half4 h;
      h.lo = __floats2half2_rn(v0, v1);
      h.hi = __floats2half2_rn(v2, v3);
      newh[i] = h;
      *(half4*)(Tk + ((size_t)n * 32 + b) * F + fbase) = h;
    }
    __syncthreads();
#pragma unroll
    for (int i = 0; i < NPT; ++i) {
      int n = threadIdx.x + i * THREADS;
      prevv[i] = cur[n];
      cur[n] = newh[i];
    }
    __syncthreads();
  }
}

// ---------------- per-b recurrence step for the tail (R5 logic, NPT=1, guarded) ----------------
template<int N>
__device__ void tail_recur(const float* __restrict__ X, const int* __restrict__ ec,
                           __half* __restrict__ Th, half4* cur, int b, int fbase, int tid)
{
  constexpr size_t SLH = (size_t)N * 32 * 32;
  const float cI = -1.0f / 6.0f;
  const float cS = -1.0f / 3.0f;
  const bool act = tid < N;
  const int n = tid;
  half4 prev, neww;
  if (act) {
    float4 xv = *(const float4*)(X + ((size_t)n * 32 + b) * 32 + fbase);
    half4 h;
    h.lo = __floats2half2_rn(xv.x, xv.y);
    h.hi = __floats2half2_rn(xv.z, xv.w);
    cur[n] = h;
  }
  __syncthreads();
#pragma unroll 1
  for (int k = 1; k <= 5; ++k) {
    __half* Tk = Th + (size_t)(k - 1) * SLH;
    if (act) {
      const int2* e2 = (const int2*)(ec + n * 6);
      int2 ea = e2[0], eb = e2[1], ez = e2[2];
      int na[6];
      na[0] = ea.x; na[1] = ea.y; na[2] = eb.x;
      na[3] = eb.y; na[4] = ez.x; na[5] = ez.y;
      float s0 = 0.f, s1 = 0.f, s2 = 0.f, s3 = 0.f;
#pragma unroll
      for (int d = 0; d < 6; ++d) {
        half4 t = cur[na[d]];
        float2 a = __half22float2(t.lo);
        float2 c = __half22float2(t.hi);
        s0 += a.x; s1 += a.y; s2 += c.x; s3 += c.y;
      }
      float v0, v1, v2, v3;
      if (k == 1) {
        v0 = cI * s0; v1 = cI * s1; v2 = cI * s2; v3 = cI * s3;
      } else {
        float2 pa = __half22float2(prev.lo);
        float2 pc = __half22float2(prev.hi);
        v0 = cS * s0 - pa.x; v1 = cS * s1 - pa.y;
        v2 = cS * s2 - pc.x; v3 = cS * s3 - pc.y;
      }
      neww.lo = __floats2half2_rn(v0, v1);
      neww.hi = __floats2half2_rn(v2, v3);
      *(half4*)(Tk + ((size_t)n * 32 + b) * 32 + fbase) = neww;
    }
    __syncthreads();
    if (act) {
      prev = cur[n];
      cur[n] = neww;
    }
    __syncthreads();
  }
}

// ---------------- TAIL: pool1 -> recur2 -> pool2 -> recur3 -> pool3 -> enc -> cls ----------------
// 32 blocks (one per batch b) x 1024 threads. Replaces 7 kernels.
struct TailP {
  const float* X1; __half* Th;
  const float *W1, *b1; const int* pc1; const float* pv1; float* X2;
  const int* ec2; const float *W2, *b2; const int* pc2; const float* pv2; float* X3;
  const int* ec3; const float *W3, *b3; const int* pc3; const float* pv3; float* X4;
  const float *encW, *encB, *clsW, *clsB; float* out;
};

__global__ void __launch_bounds__(1024, 1) tail_per_b(TailP p)
{
  const int b = blockIdx.x;          // 0..31
  const int tid = threadIdx.x;       // 0..1023
  __shared__ __align__(16) char sm[33792];   // 24KB weights + 8KB cur + 1KB misc
  float* Wsf = (float*)sm;
  __half* Wsh = (__half*)sm;
  half4* cur = (half4*)(sm + 24576);

  // ---- phase 1: pool1 (M=1024, FOUT=32): 8192 cells, 8 per thread ----
  for (int i = tid; i < 6144; i += 1024) Wsf[i] = p.W1[i];
  __syncthreads();
#pragma unroll 1
  for (int g = 0; g < 8; ++g) {
    int m = g * 128 + (tid >> 3);
    int fo4 = tid & 7;
    st_pool32<4096, 1024, 32, false, false>(p.X1, p.Th, Wsf, p.b1, p.pc1, p.pv1,
                                            p.X2, (m * 32 + b) * 8 + fo4);
  }
  __threadfence();
  __syncthreads();

  // ---- phase 2: recur2 (N=1024), 8 channel-slabs of 4 ----
#pragma unroll 1
  for (int slab = 0; slab < 8; ++slab)
    tail_recur<1024>(p.X2, p.ec2, p.Th, cur, b, slab * 4, tid);
  __threadfence();
  __syncthreads();

  // ---- phase 3: pool2 (M=256): 2048 cells, 2 per thread ----
  for (int i = tid; i < 6144; i += 1024) Wsf[i] = p.W2[i];
  __syncthreads();
#pragma unroll 1
  for (int g = 0; g < 2; ++g) {
    int m = g * 128 + (tid >> 3);
    int fo4 = tid & 7;
    st_pool32<1024, 256, 32, false, false>(p.X2, p.Th, Wsf, p.b2, p.pc2, p.pv2,
                                           p.X3, (m * 32 + b) * 8 + fo4);
  }
  __threadfence();
  __syncthreads();

  // ---- phase 4: recur3 (N=256) ----
#pragma unroll 1
  for (int slab = 0; slab < 8; ++slab)
    tail_recur<256>(p.X3, p.ec3, p.Th, cur, b, slab * 4, tid);
  __threadfence();
  __syncthreads();

  // ---- phase 5: pool3 (M=64, FOUT=64, batch-major out), weights fp16 ----
  for (int i = tid; i < 12288; i += 1024) Wsh[i] = __float2half(p.W3[i]);
  __syncthreads();
  {
    int m = tid >> 4;
    int fo4 = tid & 15;
    st_pool32<256, 64, 64, true, true>(p.X3, p.Th, Wsh, p.b3, p.pc3, p.pv3,
                                       p.X4, (m * 32 + b) * 16 + fo4);
  }
  __threadfence();
  __syncthreads();

  // ---- phase 6: encoder (split-K x8) + relu + classifier ----
  {
    int fo = tid & 127;
    int ks = tid >> 7;                       // 0..7, chunks of 512 rows
    const float* xr = p.X4 + b * 4096 + ks * 512;
    const float* w  = p.encW + (size_t)(ks * 512) * 128 + fo;
    float s = 0.f;
#pragma unroll 8
    for (int i = 0; i < 512; ++i) s += xr[i] * w[(size_t)i * 128];
    float* part = (float*)sm;                // 8*128 fp32 (weights dead)
    part[ks * 128 + fo] = s;
    __syncthreads();
    float* Hs = (float*)(sm + 4096);
    if (tid < 128) {
      float acc = p.encB[tid];
#pragma unroll
      for (int k2 = 0; k2 < 8; ++k2) acc += part[k2 * 128 + tid];
      Hs[tid] = fmaxf(acc, 0.f);
    }
    __syncthreads();
    if (tid < 10) {
      float s2 = p.clsB[tid];
#pragma unroll 4
      for (int f = 0; f < 128; ++f) s2 += Hs[f] * p.clsW[f * 10 + tid];
      p.out[b * 10 + tid] = s2;
    }
  }
}

// ============================ launcher: 9 dispatches ============================

extern "C" void kernel_launch(void* const* d_in, const int* in_sizes, int n_in,
                              void* d_out, int out_size, void* d_ws, size_t ws_size,
                              hipStream_t stream)
{
  const float* x   = (const float*)d_in[0];
  const int* ec0 = (const int*)d_in[2];
  const int* ec1 = (const int*)d_in[4];
  const int* ec2 = (const int*)d_in[6];
  const int* ec3 = (const int*)d_in[8];
  const int* pc0 = (const int*)d_in[10]; const float* pv0 = (const float*)d_in[11];
  const int* pc1 = (const int*)d_in[13]; const float* pv1 = (const float*)d_in[14];
  const int* pc2 = (const int*)d_in[16]; const float* pv2 = (const float*)d_in[17];
  const int* pc3 = (const int*)d_in[19]; const float* pv3 = (const float*)d_in[20];
  const float* W0 = (const float*)d_in[21]; const float* b0 = (const float*)d_in[22];
  const float* W1 = (const float*)d_in[23]; const float* b1 = (const float*)d_in[24];
  const float* W2 = (const float*)d_in[25]; const float* b2 = (const float*)d_in[26];
  const float* W3 = (const float*)d_in[27]; const float* b3 = (const float*)d_in[28];
  const float* encW = (const float*)d_in[29]; const float* encB = (const float*)d_in[30];
  const float* clsW = (const float*)d_in[31]; const float* clsB = (const float*)d_in[32];
  float* out = (float*)d_out;

  float* ws = (float*)d_ws;
  half4*  Xh = (half4*)ws;               // 1,048,576 floats
  __half* Th = (__half*)(ws + 1048576);  // 10,485,760 floats
  float* X1 = ws + 1048576 + 10485760;   // 4,194,304
  float* X2 = X1 + 4194304;              // 1,048,576
  float* X3 = X2 + 1048576;              // 262,144
  float* X4 = X3 + 262144;               // 131,072  ([32][4096])

  const float cI = -1.0f / 6.0f;
  const float cS = -1.0f / 3.0f;
  dim3 blk(256);
  constexpr size_t S = (size_t)16384 * 32;
  half4* T4 = (half4*)Th;

  // layer 0 (R1-verified shapes)
  transpose_h<<<dim3(2048), blk, 0, stream>>>(x, Xh);
  cheb_step_h<<<dim3(2048), blk, 0, stream>>>(Xh,       Xh,       ec0, T4,        cI,  0.f);
  cheb_step_h<<<dim3(2048), blk, 0, stream>>>(T4,       Xh,       ec0, T4 + S,    cS, -1.f);
  cheb_step_h<<<dim3(2048), blk, 0, stream>>>(T4 + S,   T4,       ec0, T4 + 2*S,  cS, -1.f);
  cheb_step_h<<<dim3(2048), blk, 0, stream>>>(T4 + 2*S, T4 + S,   ec0, T4 + 3*S,  cS, -1.f);
  cheb_step_h<<<dim3(2048), blk, 0, stream>>>(T4 + 3*S, T4 + 2*S, ec0, T4 + 4*S,  cS, -1.f);
  pool_conv_f3_h<<<dim3(4096), blk, 0, stream>>>(Xh, T4, W0, b0, pc0, pv0, X1);

  // layer 1 recurrence (R5-verified)
  cheb_recur_hh<4096, 32, 1024, 4><<<dim3(256), dim3(1024), 0, stream>>>(X1, ec1, Th);

  // fused tail: pool1..cls (replaces 7 kernels)
  TailP tp{ X1, Th,
            W1, b1, pc1, pv1, X2,
            ec2, W2, b2, pc2, pv2, X3,
            ec3, W3, b3, pc3, pv3, X4,
            encW, encB, clsW, clsB, out };
  tail_per_b<<<dim3(32), dim3(1024), 0, stream>>>(tp);
}

// Round 9
// 377.589 us; speedup vs baseline: 6.3981x; 1.7029x over previous
//
#include <hip/hip_runtime.h>
#include <hip/hip_fp16.h>
#include <cstddef>
#include <cstdint>

#define BATCH 32

// Workspace (floats):
//   Th : [0, 10,485,760)  chain planes P[6][32][3][16384]h (head), then
//        recur slices [n][32][32]h x5 for layers 1-3 (sequentially reused, R5 pattern)
//   X1 : +10,485,760  4,194,304   [4096][32][32] fp32
//   X2 : +14,680,064  1,048,576   [1024][32][32] fp32
//   X3 : +15,728,640    262,144   [256][32][32] fp32
//   X4 : +15,990,784    131,072   [32][4096] fp32 (batch-major)
//   P  : +16,121,856    524,288   encoder partials [32][128][128]
//
// 10 dispatches: chain_bc, pool0_p, recur1, pool1, recur2, pool2, recur3,
//                pool3, enc_ws, cls.  (Head = new fusion; tail = R5-verified.)

struct alignas(8) half4 { __half2 lo, hi; };

__device__ __forceinline__ void h4f(const half4 h, float f[4]) {
  float2 a = __half22float2(h.lo);
  float2 c = __half22float2(h.hi);
  f[0] = a.x; f[1] = a.y; f[2] = c.x; f[3] = c.y;
}
__device__ __forceinline__ void fma4(float4& a, float s, const float4& w) {
  a.x += s * w.x; a.y += s * w.y; a.z += s * w.z; a.w += s * w.w;
}
__device__ __forceinline__ float4 relu4(const float4& a) {
  return make_float4(fmaxf(a.x, 0.f), fmaxf(a.y, 0.f), fmaxf(a.z, 0.f), fmaxf(a.w, 0.f));
}

// ================= 1. layer-0 chain, per (b,ch) plane, LDS-resident =================
// 96 blocks x 1024 thr, 32 KB LDS. Plane P[k][b][ch][n] fp16, k=0 is T0=x.
// Replaces transpose + 5 cheb_step dispatches; gathers are ds_read_u16.
__global__ void __launch_bounds__(1024) chain_bc(
    const float* __restrict__ x, const int* __restrict__ ec,
    __half* __restrict__ P)
{
  __shared__ __half cur[16384];
  const int b  = blockIdx.x & 31;
  const int ch = blockIdx.x >> 5;      // 0..2
  const int tid = threadIdx.x;
  float prevv[16], newv[16];
  // T0 = x channel plane
  {
    __half* p0 = P + ((size_t)(0 * 32 + b) * 3 + ch) * 16384;
#pragma unroll
    for (int i = 0; i < 16; ++i) {
      int n = tid + (i << 10);
      __half h = __float2half(x[((size_t)b * 16384 + n) * 3 + ch]);
      cur[n] = h;
      p0[n] = h;
    }
  }
  __syncthreads();
  const float cI = -1.0f / 6.0f, cS = -1.0f / 3.0f;
#pragma unroll 1
  for (int k = 1; k <= 5; ++k) {
    __half* pk = P + ((size_t)(k * 32 + b) * 3 + ch) * 16384;
#pragma unroll
    for (int i = 0; i < 16; ++i) {
      int n = tid + (i << 10);
      const int2* e2 = (const int2*)(ec + n * 6);
      int2 ea = e2[0], eb = e2[1], ez = e2[2];
      float s = __half2float(cur[ea.x]) + __half2float(cur[ea.y])
              + __half2float(cur[eb.x]) + __half2float(cur[eb.y])
              + __half2float(cur[ez.x]) + __half2float(cur[ez.y]);
      float v = (k == 1) ? (cI * s) : (cS * s - prevv[i]);
      newv[i] = v;
      pk[n] = __float2half(v);
    }
    __syncthreads();
#pragma unroll
    for (int i = 0; i < 16; ++i) {
      int n = tid + (i << 10);
      prevv[i] = __half2float(cur[n]);   // own slot still = T_{k-1}
      cur[n] = __float2half(newv[i]);    // T_k
    }
    __syncthreads();
  }
}

// ================= 2. pool0 from planes =================
__global__ void __launch_bounds__(256) pool0_p(
    const __half* __restrict__ P, const float* __restrict__ W,
    const float* __restrict__ bias, const int* __restrict__ pc,
    const float* __restrict__ pv, float* __restrict__ out)
{
  constexpr int F4 = 8;                 // FOUT=32
  __shared__ float Ws[576];
  for (int i = threadIdx.x; i < 576; i += 256) Ws[i] = W[i];
  __syncthreads();
  const float4* Ws4 = (const float4*)Ws;
  int t = blockIdx.x * 256 + threadIdx.x;     // 4096*32*8
  int fo4 = t % F4;
  int b   = (t / F4) % BATCH;
  int m   = t / (F4 * BATCH);
  int c0 = pc[m * 3 + 0], c1 = pc[m * 3 + 1], c2 = pc[m * 3 + 2];
  float v0 = pv[m * 3 + 0], v1 = pv[m * 3 + 1], v2 = pv[m * 3 + 2];
  float4 bi = ((const float4*)bias)[fo4];
  float4 a0 = bi, a1 = bi, a2 = bi;
  const size_t bbase = (size_t)b * 3 * 16384;
#pragma unroll
  for (int k = 0; k < 6; ++k) {
    const __half* pk = P + (size_t)k * 32 * 3 * 16384 + bbase;
#pragma unroll
    for (int f = 0; f < 3; ++f) {
      const __half* pl = pk + (size_t)f * 16384;
      float r0 = __half2float(pl[c0]);
      float r1 = __half2float(pl[c1]);
      float r2 = __half2float(pl[c2]);
      float4 w = Ws4[(k * 3 + f) * F4 + fo4];
      fma4(a0, r0, w);
      fma4(a1, r1, w);
      fma4(a2, r2, w);
    }
  }
  a0 = relu4(a0); a1 = relu4(a1); a2 = relu4(a2);
  float4 acc;
  acc.x = v0*a0.x + v1*a1.x + v2*a2.x;
  acc.y = v0*a0.y + v1*a1.y + v2*a2.y;
  acc.z = v0*a0.z + v1*a1.z + v2*a2.z;
  acc.w = v0*a0.w + v1*a1.w + v2*a2.w;
  ((float4*)out)[((size_t)m * BATCH + b) * F4 + fo4] = acc;   // node-major fp32
}

// ================= 3. LDS Cheb recurrence, layers 1-3 (R5-verified, unchanged) =================
template<int N, int F, int THREADS, int MINW>
__global__ void __launch_bounds__(THREADS, MINW) cheb_recur_hh(
    const float* __restrict__ X,    // node-major fp32 [N][32][F]
    const int* __restrict__ ec,     // [N][6]
    __half* __restrict__ Th)        // 5 slices, [n][32][F] halves
{
  constexpr int NPT = N / THREADS;
  __shared__ half4 cur[N];                     // 8 B per node
  const float cI = -1.0f / 6.0f;
  const float cS = -1.0f / 3.0f;
  const int b = blockIdx.x & 31;
  const int fbase = (blockIdx.x >> 5) * 4;     // slab of 4 features
  constexpr size_t SLH = (size_t)N * 32 * F;   // halves per slice
  half4 prevv[NPT], newh[NPT];
#pragma unroll
  for (int i = 0; i < NPT; ++i) {
    int n = threadIdx.x + i * THREADS;
    float4 xv = *(const float4*)(X + ((size_t)n * 32 + b) * F + fbase);
    half4 h;
    h.lo = __floats2half2_rn(xv.x, xv.y);
    h.hi = __floats2half2_rn(xv.z, xv.w);
    cur[n] = h;
  }
  __syncthreads();
#pragma unroll 1
  for (int k = 1; k <= 5; ++k) {
    __half* Tk = Th + (size_t)(k - 1) * SLH;
#pragma unroll
    for (int i = 0; i < NPT; ++i) {
      int n = threadIdx.x + i * THREADS;
      const int2* e2 = (const int2*)(ec + n * 6);
      int2 ea = e2[0], eb = e2[1], ez = e2[2];
      int na[6];
      na[0] = ea.x; na[1] = ea.y; na[2] = eb.x;
      na[3] = eb.y; na[4] = ez.x; na[5] = ez.y;
      float s0 = 0.f, s1 = 0.f, s2 = 0.f, s3 = 0.f;
#pragma unroll
      for (int d = 0; d < 6; ++d) {
        half4 t = cur[na[d]];                  // ds_read_b64
        float2 a = __half22float2(t.lo);
        float2 c = __half22float2(t.hi);
        s0 += a.x; s1 += a.y; s2 += c.x; s3 += c.y;
      }
      float v0, v1, v2, v3;
      if (k == 1) {
        v0 = cI * s0; v1 = cI * s1; v2 = cI * s2; v3 = cI * s3;
      } else {
        float2 pa = __half22float2(prevv[i].lo);
        float2 pc = __half22float2(prevv[i].hi);
        v0 = cS * s0 - pa.x; v1 = cS * s1 - pa.y;
        v2 = cS * s2 - pc.x; v3 = cS * s3 - pc.y;
      }
      half4 h;
      h.lo = __floats2half2_rn(v0, v1);
      h.hi = __floats2half2_rn(v2, v3);
      newh[i] = h;
      *(half4*)(Tk + ((size_t)n * 32 + b) * F + fbase) = h;
    }
    __syncthreads();   // all gathers of T_{k-1} complete
#pragma unroll
    for (int i = 0; i < NPT; ++i) {
      int n = threadIdx.x + i * THREADS;
      prevv[i] = cur[n];                       // own slot still = T_{k-1}
      cur[n] = newh[i];                        // T_k -> cur
    }
    __syncthreads();
  }
}

// ================= 4. fused pool(relu(conv)), FIN=32 (R5-verified, unchanged) =================
template<int N, int M, int FOUT, bool OUT_BM>
__global__ void __launch_bounds__(256) pool_conv_v32_h(
    const float* __restrict__ X, const __half* __restrict__ Th,
    const float* __restrict__ W, const float* __restrict__ bias,
    const int* __restrict__ pc, const float* __restrict__ pv,
    float* __restrict__ out)
{
  constexpr int FIN = 32;
  constexpr int F4 = FOUT / 4;
  constexpr size_t SLH = (size_t)N * 32 * FIN;   // halves per slice
  __shared__ float Ws[6 * FIN * FOUT];           // 24 KB or 48 KB
  for (int i = threadIdx.x; i < 6 * FIN * FOUT; i += 256) Ws[i] = W[i];
  __syncthreads();
  const float4* Ws4 = (const float4*)Ws;
  const float4* X4p = (const float4*)X;
  int t = blockIdx.x * 256 + threadIdx.x;        // exact grid: M*32*F4
  int fo4 = t % F4;
  int b   = (t / F4) % BATCH;
  int m   = t / (F4 * BATCH);
  int c0 = pc[m * 3 + 0], c1 = pc[m * 3 + 1], c2 = pc[m * 3 + 2];
  float v0 = pv[m * 3 + 0], v1 = pv[m * 3 + 1], v2 = pv[m * 3 + 2];
  float4 bi = ((const float4*)bias)[fo4];
  float4 a0 = bi, a1 = bi, a2 = bi;
  // k = 0 from fp32 X
  {
    const float4* r0 = X4p + ((size_t)c0 * BATCH + b) * 8;
    const float4* r1 = X4p + ((size_t)c1 * BATCH + b) * 8;
    const float4* r2 = X4p + ((size_t)c2 * BATCH + b) * 8;
#pragma unroll
    for (int fi = 0; fi < 8; ++fi) {
      float4 t0 = r0[fi], t1 = r1[fi], t2 = r2[fi];
#pragma unroll
      for (int ff = 0; ff < 4; ++ff) {
        float4 w = Ws4[(fi * 4 + ff) * F4 + fo4];
        fma4(a0, ((const float*)&t0)[ff], w);
        fma4(a1, ((const float*)&t1)[ff], w);
        fma4(a2, ((const float*)&t2)[ff], w);
      }
    }
  }
  // k = 1..5 from fp16 T
#pragma unroll 1
  for (int k = 1; k < 6; ++k) {
    const half4* base = (const half4*)(Th + (size_t)(k - 1) * SLH);
    const half4* r0 = base + ((size_t)c0 * 32 + b) * 8;
    const half4* r1 = base + ((size_t)c1 * 32 + b) * 8;
    const half4* r2 = base + ((size_t)c2 * 32 + b) * 8;
#pragma unroll
    for (int q = 0; q < 8; ++q) {
      float f0[4], f1[4], f2[4];
      h4f(r0[q], f0); h4f(r1[q], f1); h4f(r2[q], f2);
#pragma unroll
      for (int ff = 0; ff < 4; ++ff) {
        float4 w = Ws4[((k * 32) + q * 4 + ff) * F4 + fo4];
        fma4(a0, f0[ff], w);
        fma4(a1, f1[ff], w);
        fma4(a2, f2[ff], w);
      }
    }
  }
  a0 = relu4(a0); a1 = relu4(a1); a2 = relu4(a2);
  float4 acc;
  acc.x = v0*a0.x + v1*a1.x + v2*a2.x;
  acc.y = v0*a0.y + v1*a1.y + v2*a2.y;
  acc.z = v0*a0.z + v1*a1.z + v2*a2.z;
  acc.w = v0*a0.w + v1*a1.w + v2*a2.w;
  size_t oi = OUT_BM ? (((size_t)b * M + m) * F4 + fo4) : (((size_t)m * BATCH + b) * F4 + fo4);
  ((float4*)out)[oi] = acc;
}

// ================= 5. weight-stationary encoder partial (R5-verified) =================
__global__ void __launch_bounds__(128) encoder_partial_ws(
    const float* __restrict__ Xf, const float* __restrict__ encW,
    float* __restrict__ partial)
{
  int j  = blockIdx.x;          // i-chunk 0..127
  int fo = threadIdx.x;         // 0..127
  int i0 = j * 32;
  float w[32];
#pragma unroll
  for (int i = 0; i < 32; ++i) w[i] = encW[(size_t)(i0 + i) * 128 + fo];
#pragma unroll 1
  for (int b = 0; b < 32; ++b) {
    const float* xr = Xf + b * 4096 + i0;     // wave-uniform -> s_loads
    float s = 0.f;
#pragma unroll
    for (int i = 0; i < 32; ++i) s += xr[i] * w[i];
    partial[((size_t)b * 128 + j) * 128 + fo] = s;
  }
}

// ================= 6. fused encoder-reduce + relu + classifier (R5-verified) =================
__global__ void __launch_bounds__(128) encoder_reduce_cls(
    const float* __restrict__ partial, const float* __restrict__ encB,
    const float* __restrict__ clsW, const float* __restrict__ clsB,
    float* __restrict__ out)
{
  int b = blockIdx.x;           // 0..31
  int fo = threadIdx.x;         // 0..127
  float acc = encB[fo];
#pragma unroll 8
  for (int j = 0; j < 128; ++j) acc += partial[((size_t)b * 128 + j) * 128 + fo];
  __shared__ float Hs[128];
  Hs[fo] = fmaxf(acc, 0.f);
  __syncthreads();
  if (fo < 10) {
    float s = clsB[fo];
#pragma unroll 4
    for (int f = 0; f < 128; ++f) s += Hs[f] * clsW[f * 10 + fo];
    out[b * 10 + fo] = s;
  }
}

// ================= launcher: 10 dispatches =================

extern "C" void kernel_launch(void* const* d_in, const int* in_sizes, int n_in,
                              void* d_out, int out_size, void* d_ws, size_t ws_size,
                              hipStream_t stream)
{
  const float* x   = (const float*)d_in[0];
  const int* ec0 = (const int*)d_in[2];
  const int* ec1 = (const int*)d_in[4];
  const int* ec2 = (const int*)d_in[6];
  const int* ec3 = (const int*)d_in[8];
  const int* pc0 = (const int*)d_in[10]; const float* pv0 = (const float*)d_in[11];
  const int* pc1 = (const int*)d_in[13]; const float* pv1 = (const float*)d_in[14];
  const int* pc2 = (const int*)d_in[16]; const float* pv2 = (const float*)d_in[17];
  const int* pc3 = (const int*)d_in[19]; const float* pv3 = (const float*)d_in[20];
  const float* W0 = (const float*)d_in[21]; const float* b0 = (const float*)d_in[22];
  const float* W1 = (const float*)d_in[23]; const float* b1 = (const float*)d_in[24];
  const float* W2 = (const float*)d_in[25]; const float* b2 = (const float*)d_in[26];
  const float* W3 = (const float*)d_in[27]; const float* b3 = (const float*)d_in[28];
  const float* encW = (const float*)d_in[29]; const float* encB = (const float*)d_in[30];
  const float* clsW = (const float*)d_in[31]; const float* clsB = (const float*)d_in[32];
  float* out = (float*)d_out;

  float* ws = (float*)d_ws;
  __half* Th = (__half*)ws;              // planes, then recur slices (sequential reuse)
  float* X1 = ws + 10485760;             // 4,194,304
  float* X2 = X1 + 4194304;              // 1,048,576
  float* X3 = X2 + 1048576;              // 262,144
  float* X4 = X3 + 262144;               // 131,072  ([32][4096])
  float* P  = X4 + 131072;               // 524,288  ([32][128][128])

  dim3 blk(256);

  // ---- head: fused layer-0 chain + pool0 (new; replaces 7 dispatches) ----
  chain_bc<<<dim3(96), dim3(1024), 0, stream>>>(x, ec0, Th);
  pool0_p<<<dim3(4096), blk, 0, stream>>>(Th, W0, b0, pc0, pv0, X1);

  // ---- tail: R5-verified kernels, byte-identical ----
  cheb_recur_hh<4096, 32, 1024, 4><<<dim3(256), dim3(1024), 0, stream>>>(X1, ec1, Th);
  pool_conv_v32_h<4096, 1024, 32, false><<<dim3(1024), blk, 0, stream>>>(
      X1, Th, W1, b1, pc1, pv1, X2);

  cheb_recur_hh<1024, 32, 256, 4><<<dim3(256), blk, 0, stream>>>(X2, ec2, Th);
  pool_conv_v32_h<1024, 256, 32, false><<<dim3(256), blk, 0, stream>>>(
      X2, Th, W2, b2, pc2, pv2, X3);

  cheb_recur_hh<256, 32, 256, 4><<<dim3(256), blk, 0, stream>>>(X3, ec3, Th);
  pool_conv_v32_h<256, 64, 64, true><<<dim3(128), blk, 0, stream>>>(
      X3, Th, W3, b3, pc3, pv3, X4);

  encoder_partial_ws<<<dim3(128), dim3(128), 0, stream>>>(X4, encW, P);
  encoder_reduce_cls<<<dim3(32), dim3(128), 0, stream>>>(P, encB, clsW, clsB, out);
}